// Round 4
// baseline (5753.374 us; speedup 1.0000x reference)
//
#include <hip/hip_runtime.h>
#include <hip/hip_bf16.h>

#define BATCH  256
#define TSTEPS 501
#define NIN1   17
#define NH     256
#define DPAR   69888
#define KAUG   288   // 256 h + 17 x + 15 pad
#define HKAUG  144
#define FPIT   100

typedef _Float16 f16;
typedef f16   f16x2  __attribute__((ext_vector_type(2)));
typedef f16   f16x8  __attribute__((ext_vector_type(8)));
typedef short bf16x8 __attribute__((ext_vector_type(8)));
typedef float f32x4  __attribute__((ext_vector_type(4)));

__device__ __forceinline__ float dot2(unsigned w, unsigned v, float c) {
#if __has_builtin(__builtin_amdgcn_fdot2)
  return __builtin_amdgcn_fdot2(__builtin_bit_cast(f16x2, w), __builtin_bit_cast(f16x2, v), c, false);
#else
  f16x2 a = __builtin_bit_cast(f16x2, w), b = __builtin_bit_cast(f16x2, v);
  return c + (float)a[0] * (float)b[0] + (float)a[1] * (float)b[1];
#endif
}

__device__ __forceinline__ unsigned packh2(float a, float b) {
  f16x2 v; v[0] = (f16)a; v[1] = (f16)b;
  return __builtin_bit_cast(unsigned, v);
}

__device__ __forceinline__ short f2bf(float x) {
  __hip_bfloat16 b = __float2bfloat16(x);
  return __builtin_bit_cast(short, b);
}
__device__ __forceinline__ float bfs2f(short s) {
  return __bfloat162float(__builtin_bit_cast(__hip_bfloat16, s));
}

__device__ __forceinline__ float sigm(float x) { return 1.f / (1.f + __expf(-x)); }
__device__ __forceinline__ float tanh_f(float x) {
  float e = __expf(2.f * x);
  return 1.f - 2.f / (e + 1.f);
}

// ---------------------------------------------------------------------------
// Kernel 1: GRU recurrence. One block per batch element, 512 threads.
// fp32 inputs; weights packed to f16 VGPR pairs. Thread (j,hf) owns the
// hf-half of gate rows {j, j+256, j+512}. [h|x] broadcast vector in LDS (f16).
// ---------------------------------------------------------------------------
__global__ __launch_bounds__(512, 2) void gru_kernel(
    const float* __restrict__ u,
    const float* __restrict__ gWih,
    const float* __restrict__ gWhh,
    const float* __restrict__ gbih,
    const float* __restrict__ gbhh,
    short* __restrict__ A2)   // bf16 hi/lo pair output, bit-cast as short
{
  const int b   = blockIdx.x;
  const int tid = threadIdx.x;
  const int j   = tid & 255;
  const int hf  = tid >> 8;

  __shared__ __align__(16) unsigned vecu[KAUG / 2];  // [h(256) | x(17) | pad] f16
  __shared__ float part_r[NH], part_z[NH], part_nh[NH], part_ni[NH];

  unsigned wr[72], wz[72], wnh[72], wni[9];

  auto augw = [&](int g, int k) -> float {
    if (k < NH) return gWhh[g * NH + k];
    if (k < NH + NIN1) return gWih[g * NIN1 + (k - NH)];
    return 0.f;
  };

#pragma unroll
  for (int p = 0; p < 72; ++p) {
    int k = hf * HKAUG + 2 * p;
    wr[p] = packh2(augw(j, k), augw(j, k + 1));
    wz[p] = packh2(augw(j + 256, k), augw(j + 256, k + 1));
    float n0 = (k     < NH) ? gWhh[(j + 512) * NH + k]     : 0.f;
    float n1 = (k + 1 < NH) ? gWhh[(j + 512) * NH + k + 1] : 0.f;
    wnh[p] = packh2(n0, n1);  // hn dot: only k<256 (hidden part)
  }
#pragma unroll
  for (int p = 0; p < 9; ++p) {
    float a = 0.f, c = 0.f;
    if (hf == 1) {
      a = gWih[(j + 512) * NIN1 + 2 * p];
      if (2 * p + 1 < NIN1) c = gWih[(j + 512) * NIN1 + 2 * p + 1];
    }
    wni[p] = packh2(a, c);    // inn dot (input part), owned by hf==1
  }
  const float bias_r  = gbih[j]       + gbhh[j];
  const float bias_z  = gbih[j + 256] + gbhh[j + 256];
  const float bias_in = gbih[j + 512];
  const float bias_hn = gbhh[j + 512];

  float h = 0.f;
  {
    f16* vech = (f16*)vecu;
    if (hf == 0) {
      vech[j] = (f16)0.f;                       // h0 = 0
    } else if (j < 32) {
      float xv = (j < NIN1) ? u[((size_t)b * TSTEPS + 0) * NIN1 + j] : 0.f;
      vech[NH + j] = (f16)xv;                   // x_0 + zero pad
    }
  }
  __syncthreads();

  for (int t = 0; t < TSTEPS; ++t) {
    float xnext = 0.f;
    if (hf == 0 && j < NIN1 && t + 1 < TSTEPS)
      xnext = u[((size_t)b * TSTEPS + t + 1) * NIN1 + j];  // prefetch

    float accR = 0.f, accZ = 0.f, accNH = 0.f, accNI = 0.f;
    const uint4* v4 = (const uint4*)(vecu + hf * (HKAUG / 2));
#pragma unroll
    for (int c = 0; c < 18; ++c) {
      uint4 v = v4[c];
      accR  = dot2(wr[4 * c + 0], v.x, accR);
      accR  = dot2(wr[4 * c + 1], v.y, accR);
      accR  = dot2(wr[4 * c + 2], v.z, accR);
      accR  = dot2(wr[4 * c + 3], v.w, accR);
      accZ  = dot2(wz[4 * c + 0], v.x, accZ);
      accZ  = dot2(wz[4 * c + 1], v.y, accZ);
      accZ  = dot2(wz[4 * c + 2], v.z, accZ);
      accZ  = dot2(wz[4 * c + 3], v.w, accZ);
      accNH = dot2(wnh[4 * c + 0], v.x, accNH);
      accNH = dot2(wnh[4 * c + 1], v.y, accNH);
      accNH = dot2(wnh[4 * c + 2], v.z, accNH);
      accNH = dot2(wnh[4 * c + 3], v.w, accNH);
    }
    if (hf == 1) {
      const uint4* vi = (const uint4*)(vecu + 128);  // x-part of vec
      uint4 va = vi[0], vb = vi[1];
      accNI = dot2(wni[0], va.x, accNI);
      accNI = dot2(wni[1], va.y, accNI);
      accNI = dot2(wni[2], va.z, accNI);
      accNI = dot2(wni[3], va.w, accNI);
      accNI = dot2(wni[4], vb.x, accNI);
      accNI = dot2(wni[5], vb.y, accNI);
      accNI = dot2(wni[6], vb.z, accNI);
      accNI = dot2(wni[7], vb.w, accNI);
      accNI = dot2(wni[8], vecu[136], accNI);
      part_r[j] = accR; part_z[j] = accZ; part_nh[j] = accNH; part_ni[j] = accNI;
    }
    __syncthreads();
    if (hf == 0) {
      float rp  = accR  + part_r[j]  + bias_r;
      float zp  = accZ  + part_z[j]  + bias_z;
      float hn  = accNH + part_nh[j] + bias_hn;
      float inn = part_ni[j] + bias_in;
      float r = sigm(rp), z = sigm(zp);
      float n = tanh_f(inn + r * hn);
      h = (1.f - z) * n + z * h;
      f16* vech = (f16*)vecu;
      vech[j] = (f16)h;
      if (j < NIN1) vech[NH + j] = (f16)xnext;
    }
    __syncthreads();
  }

  if (hf == 0) {  // hT as bf16 hi/lo pair -> A-operand of the dparams GEMM
    short hi = f2bf(h);
    A2[(size_t)b * 512 + j]       = hi;
    A2[(size_t)b * 512 + 256 + j] = f2bf(h - bfs2f(hi));
  }
}

// ---------------------------------------------------------------------------
// Kernel 2 (chunked over batch): for b in [mb, mb+nb):
// dp[b-mb] = [h_hi|h_lo] @ [Wage;Wage] + bage + {Wih|Whh|bih+bhh}, stored f16.
// Wage is fp32 -> converted to bf16 while staging to LDS. 128x128 tiles,
// 4 waves x (4x4) 16x16x32 bf16 MFMA. dp row: [Bm(4096) | A(65536) | C(256)].
// ---------------------------------------------------------------------------
__global__ __launch_bounds__(256, 2) void gemm_kernel(
    const short* __restrict__ A2,
    const float* __restrict__ Wage,
    const float* __restrict__ bage,
    const float* __restrict__ Wih,
    const float* __restrict__ Whh,
    const float* __restrict__ bih,
    const float* __restrict__ bhh,
    f16* __restrict__ dp, int mb, int nb)
{
  __shared__ __align__(16) short As[128 * 40];
  __shared__ __align__(16) short Bs[128 * 40];
  const int tid = threadIdx.x;
  const int n0 = blockIdx.x * 128, m0 = blockIdx.y * 128;
  const int w = tid >> 6, l = tid & 63;
  const int wm = w & 1, wn = w >> 1;
  const int lm = l & 15, lq = l >> 4;

  f32x4 acc[4][4] = {};

  for (int k0 = 0; k0 < 512; k0 += 32) {
    const int ksrc = k0 & 255;
#pragma unroll
    for (int r = 0; r < 2; ++r) {
      int idx = r * 256 + tid;
      int row = idx >> 2, q = idx & 3;
      int rowg = mb + m0 + row; if (rowg > 255) rowg = 255;   // clamp staging
      *((uint4*)(As + row * 40 + q * 8)) =
          *((const uint4*)(A2 + (size_t)rowg * 512 + k0 + q * 8));
      const float* wsrc = Wage + (size_t)(n0 + row) * 256 + ksrc + q * 8;
      f32x4 w0 = *((const f32x4*)wsrc);
      f32x4 w1 = *((const f32x4*)(wsrc + 4));
      bf16x8 pk;
      pk[0] = f2bf(w0[0]); pk[1] = f2bf(w0[1]); pk[2] = f2bf(w0[2]); pk[3] = f2bf(w0[3]);
      pk[4] = f2bf(w1[0]); pk[5] = f2bf(w1[1]); pk[6] = f2bf(w1[2]); pk[7] = f2bf(w1[3]);
      *((bf16x8*)(Bs + row * 40 + q * 8)) = pk;
    }
    __syncthreads();
    bf16x8 af[4], bfr[4];
#pragma unroll
    for (int i = 0; i < 4; ++i)
      af[i] = *((const bf16x8*)(As + (wm * 64 + i * 16 + lm) * 40 + lq * 8));
#pragma unroll
    for (int i = 0; i < 4; ++i)
      bfr[i] = *((const bf16x8*)(Bs + (wn * 64 + i * 16 + lm) * 40 + lq * 8));
#pragma unroll
    for (int i = 0; i < 4; ++i)
#pragma unroll
      for (int jn = 0; jn < 4; ++jn)
        acc[i][jn] = __builtin_amdgcn_mfma_f32_16x16x32_bf16(af[i], bfr[jn], acc[i][jn], 0, 0, 0);
    __syncthreads();
  }

  // fused repack: per-column additive term (4 columns per lane)
  float addv[4];
#pragma unroll
  for (int jn = 0; jn < 4; ++jn) {
    int d = n0 + wn * 64 + jn * 16 + lm;
    float a = bage[d];
    if (d < 4096)       a += Wih[d];
    else if (d < 69632) a += Whh[d - 4096];
    else                a += bih[d - 69632] + bhh[d - 69632];
    addv[jn] = a;
  }

#pragma unroll
  for (int i = 0; i < 4; ++i)
#pragma unroll
    for (int jn = 0; jn < 4; ++jn)
#pragma unroll
      for (int rr = 0; rr < 4; ++rr) {
        int mloc = m0 + wm * 64 + i * 16 + lq * 4 + rr;  // C/D: row=(lane>>4)*4+reg
        int n = n0 + wn * 64 + jn * 16 + lm;             //      col=lane&15
        if (mloc < nb)
          dp[(size_t)mloc * DPAR + n] = (f16)(acc[i][jn][rr] + addv[jn]);
      }
}

// ---------------------------------------------------------------------------
// Kernel 3 (chunked): fixed point (100) + Euler (500) + fused Wout projection.
// One block per b; thread j holds its full fp32 A-row in 256 VGPRs
// (1 wave/SIMD -> 512-reg budget); x broadcast via LDS float4 reads.
// ---------------------------------------------------------------------------
__global__ __launch_bounds__(256, 1) void dyn_kernel(
    const f16* __restrict__ dp, int mb,
    const float* __restrict__ u,
    const float* __restrict__ tau,
    const float* __restrict__ Wout,
    const float* __restrict__ bout,
    float* __restrict__ out)
{
  const int b = mb + blockIdx.x;
  const int j = threadIdx.x;
  const f16* __restrict__ base = dp + (size_t)blockIdx.x * DPAR;

  float Arow[256];
#pragma unroll
  for (int c = 0; c < 32; ++c) {
    f16x8 v = *((const f16x8*)(base + 4096 + j * 256 + c * 8));
#pragma unroll
    for (int i = 0; i < 8; ++i) Arow[8 * c + i] = (float)v[i];
  }
  float Bm[16];
#pragma unroll
  for (int i = 0; i < 16; ++i) Bm[i] = (float)base[j * 16 + i];
  const float Cc = (float)base[69632 + j];
  const float et = __expf(tau[j]);
  const float inv_et = 1.f / et;
  float wo[8];
#pragma unroll
  for (int o = 0; o < 8; ++o) wo[o] = Wout[o * 256 + j];
  const float bo = (j < 8) ? bout[j] : 0.f;

  __shared__ __align__(16) float xv[256];
  __shared__ float unb[16];
  __shared__ float projp[4][8];

  if (j < 16) unb[j] = u[((size_t)b * TSTEPS + 0) * NIN1 + j];
  xv[j] = 0.f;
  __syncthreads();

  float bu0 = 0.f;
#pragma unroll
  for (int i = 0; i < 16; ++i) bu0 += Bm[i] * unb[i];

  float x = 0.f;
  for (int it = 0; it < FPIT; ++it) {
    float acc = bu0 + Cc;
#pragma unroll
    for (int c = 0; c < 64; ++c) {
      f32x4 v = *((const f32x4*)(xv + 4 * c));
      acc += Arow[4 * c] * v[0] + Arow[4 * c + 1] * v[1] + Arow[4 * c + 2] * v[2] + Arow[4 * c + 3] * v[3];
    }
    x = et * tanh_f(acc);
    __syncthreads();
    xv[j] = x;
    __syncthreads();
  }

  const int lane = j & 63, wv = j >> 6;
  // t = 0 projection (x0)
  {
#pragma unroll
    for (int o = 0; o < 8; ++o) {
      float p = x * wo[o];
#pragma unroll
      for (int off = 32; off > 0; off >>= 1) p += __shfl_down(p, off, 64);
      if (lane == 0) projp[wv][o] = p;
    }
    __syncthreads();
    if (j < 8)
      out[((size_t)b * TSTEPS + 0) * 8 + j] =
          projp[0][j] + projp[1][j] + projp[2][j] + projp[3][j] + bo;
  }

  for (int k = 0; k < TSTEPS - 1; ++k) {
    float bu = 0.f;
#pragma unroll
    for (int i = 0; i < 16; ++i) bu += Bm[i] * unb[i];  // Bu[:,k] on the fly
    float acc = bu + Cc;
#pragma unroll
    for (int c = 0; c < 64; ++c) {
      f32x4 v = *((const f32x4*)(xv + 4 * c));
      acc += Arow[4 * c] * v[0] + Arow[4 * c + 1] * v[1] + Arow[4 * c + 2] * v[2] + Arow[4 * c + 3] * v[3];
    }
    float unext = 0.f;
    if (j < 16 && k + 1 < TSTEPS - 1)
      unext = u[((size_t)b * TSTEPS + (k + 1)) * NIN1 + j];
    float xn = x + tanh_f(acc) - x * inv_et;
    __syncthreads();
    xv[j] = xn; x = xn;
    if (j < 16) unb[j] = unext;
    __syncthreads();
    // projection for t = k+1
#pragma unroll
    for (int o = 0; o < 8; ++o) {
      float p = x * wo[o];
#pragma unroll
      for (int off = 32; off > 0; off >>= 1) p += __shfl_down(p, off, 64);
      if (lane == 0) projp[wv][o] = p;
    }
    __syncthreads();
    if (j < 8)
      out[((size_t)b * TSTEPS + (k + 1)) * 8 + j] =
          projp[0][j] + projp[1][j] + projp[2][j] + projp[3][j] + bo;
  }
}

// ---------------------------------------------------------------------------
extern "C" void kernel_launch(void* const* d_in, const int* in_sizes, int n_in,
                              void* d_out, int out_size, void* d_ws, size_t ws_size,
                              hipStream_t stream)
{
  const float* u    = (const float*)d_in[0];
  const float* gWih = (const float*)d_in[1];
  const float* gWhh = (const float*)d_in[2];
  const float* gbih = (const float*)d_in[3];
  const float* gbhh = (const float*)d_in[4];
  const float* Wage = (const float*)d_in[5];
  const float* bage = (const float*)d_in[6];
  const float* Wih  = (const float*)d_in[7];
  const float* Whh  = (const float*)d_in[8];
  const float* bih  = (const float*)d_in[9];
  const float* bhh  = (const float*)d_in[10];
  const float* tau  = (const float*)d_in[11];
  const float* Wout = (const float*)d_in[12];
  const float* bout = (const float*)d_in[13];
  float* out = (float*)d_out;

  // ws layout: [dp chunk: bpc * DPAR f16][...][A2: 256*512 bf16 at the tail]
  const size_t A2_BYTES = (size_t)BATCH * 512 * 2;              // 256 KiB
  size_t a2_off = (ws_size > A2_BYTES + 4096)
                    ? ((ws_size - A2_BYTES) & ~(size_t)255) : 0;
  short* A2 = (short*)((char*)d_ws + a2_off);
  f16* dp = (f16*)d_ws;

  int bpc = (int)(a2_off / ((size_t)DPAR * sizeof(f16)));       // batch rows per chunk
  if (bpc < 1)     bpc = 1;        // degenerate tiny-ws fallback
  if (bpc > BATCH) bpc = BATCH;

  gru_kernel<<<BATCH, 512, 0, stream>>>(u, gWih, gWhh, gbih, gbhh, A2);

  for (int mb = 0; mb < BATCH; mb += bpc) {
    int nb = BATCH - mb; if (nb > bpc) nb = bpc;
    dim3 gg(DPAR / 128, (nb + 127) / 128);
    gemm_kernel<<<gg, 256, 0, stream>>>(A2, Wage, bage, Wih, Whh, bih, bhh, dp, mb, nb);
    dyn_kernel<<<nb, 256, 0, stream>>>(dp, mb, u, tau, Wout, bout, out);
  }
}

// Round 5
// 2933.090 us; speedup vs baseline: 1.9615x; 1.9615x over previous
//
#include <hip/hip_runtime.h>
#include <hip/hip_bf16.h>

#define BATCH  256
#define TSTEPS 501
#define NIN1   17
#define NH     256
#define DPAR   69888
#define KAUG   288   // 256 h + 17 x + 15 pad
#define HKAUG  144
#define FPIT   100

typedef _Float16 f16;
typedef f16   f16x2  __attribute__((ext_vector_type(2)));
typedef f16   f16x8  __attribute__((ext_vector_type(8)));
typedef short bf16x8 __attribute__((ext_vector_type(8)));
typedef float f32x4  __attribute__((ext_vector_type(4)));

__device__ __forceinline__ float dot2(unsigned w, unsigned v, float c) {
#if __has_builtin(__builtin_amdgcn_fdot2)
  return __builtin_amdgcn_fdot2(__builtin_bit_cast(f16x2, w), __builtin_bit_cast(f16x2, v), c, false);
#else
  f16x2 a = __builtin_bit_cast(f16x2, w), b = __builtin_bit_cast(f16x2, v);
  return c + (float)a[0] * (float)b[0] + (float)a[1] * (float)b[1];
#endif
}

__device__ __forceinline__ unsigned packh2(float a, float b) {
  f16x2 v; v[0] = (f16)a; v[1] = (f16)b;
  return __builtin_bit_cast(unsigned, v);
}

__device__ __forceinline__ short f2bf(float x) {
  __hip_bfloat16 b = __float2bfloat16(x);
  return __builtin_bit_cast(short, b);
}
__device__ __forceinline__ float bfs2f(short s) {
  return __bfloat162float(__builtin_bit_cast(__hip_bfloat16, s));
}

__device__ __forceinline__ float sigm(float x) { return 1.f / (1.f + __expf(-x)); }
__device__ __forceinline__ float tanh_f(float x) {
  float e = __expf(2.f * x);
  return 1.f - 2.f / (e + 1.f);
}

// ---------------------------------------------------------------------------
// Kernel 1: GRU recurrence. One block per batch element, 512 threads.
// fp32 inputs; weights packed to f16 VGPR pairs. Thread (j,hf) owns the
// hf-half of gate rows {j, j+256, j+512}. [h|x] broadcast vector in LDS (f16).
// ---------------------------------------------------------------------------
__global__ __launch_bounds__(512, 2) void gru_kernel(
    const float* __restrict__ u,
    const float* __restrict__ gWih,
    const float* __restrict__ gWhh,
    const float* __restrict__ gbih,
    const float* __restrict__ gbhh,
    short* __restrict__ A2)   // bf16 hi/lo pair output, bit-cast as short
{
  const int b   = blockIdx.x;
  const int tid = threadIdx.x;
  const int j   = tid & 255;
  const int hf  = tid >> 8;

  __shared__ __align__(16) unsigned vecu[KAUG / 2];  // [h(256) | x(17) | pad] f16
  __shared__ float part_r[NH], part_z[NH], part_nh[NH], part_ni[NH];

  unsigned wr[72], wz[72], wnh[72], wni[9];

  auto augw = [&](int g, int k) -> float {
    if (k < NH) return gWhh[g * NH + k];
    if (k < NH + NIN1) return gWih[g * NIN1 + (k - NH)];
    return 0.f;
  };

#pragma unroll
  for (int p = 0; p < 72; ++p) {
    int k = hf * HKAUG + 2 * p;
    wr[p] = packh2(augw(j, k), augw(j, k + 1));
    wz[p] = packh2(augw(j + 256, k), augw(j + 256, k + 1));
    float n0 = (k     < NH) ? gWhh[(j + 512) * NH + k]     : 0.f;
    float n1 = (k + 1 < NH) ? gWhh[(j + 512) * NH + k + 1] : 0.f;
    wnh[p] = packh2(n0, n1);  // hn dot: only k<256 (hidden part)
  }
#pragma unroll
  for (int p = 0; p < 9; ++p) {
    float a = 0.f, c = 0.f;
    if (hf == 1) {
      a = gWih[(j + 512) * NIN1 + 2 * p];
      if (2 * p + 1 < NIN1) c = gWih[(j + 512) * NIN1 + 2 * p + 1];
    }
    wni[p] = packh2(a, c);    // inn dot (input part), owned by hf==1
  }
  const float bias_r  = gbih[j]       + gbhh[j];
  const float bias_z  = gbih[j + 256] + gbhh[j + 256];
  const float bias_in = gbih[j + 512];
  const float bias_hn = gbhh[j + 512];

  float h = 0.f;
  {
    f16* vech = (f16*)vecu;
    if (hf == 0) {
      vech[j] = (f16)0.f;                       // h0 = 0
    } else if (j < 32) {
      float xv = (j < NIN1) ? u[((size_t)b * TSTEPS + 0) * NIN1 + j] : 0.f;
      vech[NH + j] = (f16)xv;                   // x_0 + zero pad
    }
  }
  __syncthreads();

  for (int t = 0; t < TSTEPS; ++t) {
    float xnext = 0.f;
    if (hf == 0 && j < NIN1 && t + 1 < TSTEPS)
      xnext = u[((size_t)b * TSTEPS + t + 1) * NIN1 + j];  // prefetch

    float accR = 0.f, accZ = 0.f, accNH = 0.f, accNI = 0.f;
    const uint4* v4 = (const uint4*)(vecu + hf * (HKAUG / 2));
#pragma unroll
    for (int c = 0; c < 18; ++c) {
      uint4 v = v4[c];
      accR  = dot2(wr[4 * c + 0], v.x, accR);
      accR  = dot2(wr[4 * c + 1], v.y, accR);
      accR  = dot2(wr[4 * c + 2], v.z, accR);
      accR  = dot2(wr[4 * c + 3], v.w, accR);
      accZ  = dot2(wz[4 * c + 0], v.x, accZ);
      accZ  = dot2(wz[4 * c + 1], v.y, accZ);
      accZ  = dot2(wz[4 * c + 2], v.z, accZ);
      accZ  = dot2(wz[4 * c + 3], v.w, accZ);
      accNH = dot2(wnh[4 * c + 0], v.x, accNH);
      accNH = dot2(wnh[4 * c + 1], v.y, accNH);
      accNH = dot2(wnh[4 * c + 2], v.z, accNH);
      accNH = dot2(wnh[4 * c + 3], v.w, accNH);
    }
    if (hf == 1) {
      const uint4* vi = (const uint4*)(vecu + 128);  // x-part of vec
      uint4 va = vi[0], vb = vi[1];
      accNI = dot2(wni[0], va.x, accNI);
      accNI = dot2(wni[1], va.y, accNI);
      accNI = dot2(wni[2], va.z, accNI);
      accNI = dot2(wni[3], va.w, accNI);
      accNI = dot2(wni[4], vb.x, accNI);
      accNI = dot2(wni[5], vb.y, accNI);
      accNI = dot2(wni[6], vb.z, accNI);
      accNI = dot2(wni[7], vb.w, accNI);
      accNI = dot2(wni[8], vecu[136], accNI);
      part_r[j] = accR; part_z[j] = accZ; part_nh[j] = accNH; part_ni[j] = accNI;
    }
    __syncthreads();
    if (hf == 0) {
      float rp  = accR  + part_r[j]  + bias_r;
      float zp  = accZ  + part_z[j]  + bias_z;
      float hn  = accNH + part_nh[j] + bias_hn;
      float inn = part_ni[j] + bias_in;
      float r = sigm(rp), z = sigm(zp);
      float n = tanh_f(inn + r * hn);
      h = (1.f - z) * n + z * h;
      f16* vech = (f16*)vecu;
      vech[j] = (f16)h;
      if (j < NIN1) vech[NH + j] = (f16)xnext;
    }
    __syncthreads();
  }

  if (hf == 0) {  // hT as bf16 hi/lo pair -> A-operand of the dparams GEMM
    short hi = f2bf(h);
    A2[(size_t)b * 512 + j]       = hi;
    A2[(size_t)b * 512 + 256 + j] = f2bf(h - bfs2f(hi));
  }
}

// ---------------------------------------------------------------------------
// Kernel 2 (chunked over batch): for b in [mb, mb+nb):
// dp[b-mb] = [h_hi|h_lo] @ [Wage;Wage] + bage + {Wih|Whh|bih+bhh}, stored f16.
// Wage is fp32 -> converted to bf16 while staging to LDS. 128x128 tiles,
// 4 waves x (4x4) 16x16x32 bf16 MFMA. dp row: [Bm(4096) | A(65536) | C(256)].
// ---------------------------------------------------------------------------
__global__ __launch_bounds__(256, 2) void gemm_kernel(
    const short* __restrict__ A2,
    const float* __restrict__ Wage,
    const float* __restrict__ bage,
    const float* __restrict__ Wih,
    const float* __restrict__ Whh,
    const float* __restrict__ bih,
    const float* __restrict__ bhh,
    f16* __restrict__ dp, int mb, int nb)
{
  __shared__ __align__(16) short As[128 * 40];
  __shared__ __align__(16) short Bs[128 * 40];
  const int tid = threadIdx.x;
  const int n0 = blockIdx.x * 128, m0 = blockIdx.y * 128;
  const int w = tid >> 6, l = tid & 63;
  const int wm = w & 1, wn = w >> 1;
  const int lm = l & 15, lq = l >> 4;

  f32x4 acc[4][4] = {};

  for (int k0 = 0; k0 < 512; k0 += 32) {
    const int ksrc = k0 & 255;
#pragma unroll
    for (int r = 0; r < 2; ++r) {
      int idx = r * 256 + tid;
      int row = idx >> 2, q = idx & 3;
      int rowg = mb + m0 + row; if (rowg > 255) rowg = 255;   // clamp staging
      *((uint4*)(As + row * 40 + q * 8)) =
          *((const uint4*)(A2 + (size_t)rowg * 512 + k0 + q * 8));
      const float* wsrc = Wage + (size_t)(n0 + row) * 256 + ksrc + q * 8;
      f32x4 w0 = *((const f32x4*)wsrc);
      f32x4 w1 = *((const f32x4*)(wsrc + 4));
      bf16x8 pk;
      pk[0] = f2bf(w0[0]); pk[1] = f2bf(w0[1]); pk[2] = f2bf(w0[2]); pk[3] = f2bf(w0[3]);
      pk[4] = f2bf(w1[0]); pk[5] = f2bf(w1[1]); pk[6] = f2bf(w1[2]); pk[7] = f2bf(w1[3]);
      *((bf16x8*)(Bs + row * 40 + q * 8)) = pk;
    }
    __syncthreads();
    bf16x8 af[4], bfr[4];
#pragma unroll
    for (int i = 0; i < 4; ++i)
      af[i] = *((const bf16x8*)(As + (wm * 64 + i * 16 + lm) * 40 + lq * 8));
#pragma unroll
    for (int i = 0; i < 4; ++i)
      bfr[i] = *((const bf16x8*)(Bs + (wn * 64 + i * 16 + lm) * 40 + lq * 8));
#pragma unroll
    for (int i = 0; i < 4; ++i)
#pragma unroll
      for (int jn = 0; jn < 4; ++jn)
        acc[i][jn] = __builtin_amdgcn_mfma_f32_16x16x32_bf16(af[i], bfr[jn], acc[i][jn], 0, 0, 0);
    __syncthreads();
  }

  // fused repack: per-column additive term (4 columns per lane)
  float addv[4];
#pragma unroll
  for (int jn = 0; jn < 4; ++jn) {
    int d = n0 + wn * 64 + jn * 16 + lm;
    float a = bage[d];
    if (d < 4096)       a += Wih[d];
    else if (d < 69632) a += Whh[d - 4096];
    else                a += bih[d - 69632] + bhh[d - 69632];
    addv[jn] = a;
  }

#pragma unroll
  for (int i = 0; i < 4; ++i)
#pragma unroll
    for (int jn = 0; jn < 4; ++jn)
#pragma unroll
      for (int rr = 0; rr < 4; ++rr) {
        int mloc = m0 + wm * 64 + i * 16 + lq * 4 + rr;  // C/D: row=(lane>>4)*4+reg
        int n = n0 + wn * 64 + jn * 16 + lm;             //      col=lane&15
        if (mloc < nb)
          dp[(size_t)mloc * DPAR + n] = (f16)(acc[i][jn][rr] + addv[jn]);
      }
}

// ---------------------------------------------------------------------------
// Kernel 3 (chunked): fixed point (100) + Euler (500) + fused Wout projection.
// One block per b, 256 threads. Thread j holds its A-row as 128 PACKED f16
// pairs (128 VGPRs, no spill) consumed by v_dot2_f32_f16; x lives in LDS as
// f16 pairs. Projection: wave 0 only, segmented dot2 + 3 narrow shuffles.
// ---------------------------------------------------------------------------
__global__ __launch_bounds__(256, 2) void dyn_kernel(
    const f16* __restrict__ dp, int mb,
    const float* __restrict__ u,
    const float* __restrict__ tau,
    const float* __restrict__ Wout,
    const float* __restrict__ bout,
    float* __restrict__ out)
{
  const int b = mb + blockIdx.x;
  const int j = threadIdx.x;
  const f16* __restrict__ base = dp + (size_t)blockIdx.x * DPAR;

  uint4 Ah[32];                       // A-row: 256 f16 = 32 uint4 = 128 VGPRs
#pragma unroll
  for (int c = 0; c < 32; ++c)
    Ah[c] = *((const uint4*)(base + 4096 + j * 256 + c * 8));
  uint4 Bh0 = *((const uint4*)(base + j * 16));
  uint4 Bh1 = *((const uint4*)(base + j * 16 + 8));
  const float Cc = (float)base[69632 + j];
  const float et = __expf(tau[j]);
  const float inv_et = 1.f / et;

  // projection operands (used by wave 0): lane l -> out po, x-segment ps*32
  const int l = j & 63;
  const int po = l >> 3, ps = l & 7;
  unsigned wseg[16];
#pragma unroll
  for (int p = 0; p < 16; ++p)
    wseg[p] = packh2(Wout[po * 256 + ps * 32 + 2 * p],
                     Wout[po * 256 + ps * 32 + 2 * p + 1]);
  const float bo = bout[po];

  __shared__ __align__(16) unsigned xh[128];   // x as f16 pairs (256 vals)
  __shared__ __align__(16) unsigned uh[8];     // u_t as f16 pairs (16 vals)
  f16* xh16 = (f16*)xh;
  f16* uh16 = (f16*)uh;

  if (j < 128) xh[j] = 0u;
  if (j < 16)  uh16[j] = (f16)u[((size_t)b * TSTEPS + 0) * NIN1 + j];
  __syncthreads();

  float bu0;
  {
    uint4 ua = *((const uint4*)uh), ub = *((const uint4*)(uh + 4));
    float s0 = dot2(Bh0.x, ua.x, 0.f); s0 = dot2(Bh0.y, ua.y, s0);
    s0 = dot2(Bh0.z, ua.z, s0);        s0 = dot2(Bh0.w, ua.w, s0);
    float s1 = dot2(Bh1.x, ub.x, 0.f); s1 = dot2(Bh1.y, ub.y, s1);
    s1 = dot2(Bh1.z, ub.z, s1);        s1 = dot2(Bh1.w, ub.w, s1);
    bu0 = s0 + s1;
  }

  float x = 0.f;
  for (int it = 0; it < FPIT; ++it) {
    float a0 = 0.f, a1 = 0.f, a2 = 0.f, a3 = 0.f;
    const uint4* xv4 = (const uint4*)xh;
#pragma unroll
    for (int c = 0; c < 32; ++c) {
      uint4 v = xv4[c];
      a0 = dot2(Ah[c].x, v.x, a0);
      a1 = dot2(Ah[c].y, v.y, a1);
      a2 = dot2(Ah[c].z, v.z, a2);
      a3 = dot2(Ah[c].w, v.w, a3);
    }
    x = et * tanh_f(bu0 + Cc + ((a0 + a1) + (a2 + a3)));
    __syncthreads();
    xh16[j] = (f16)x;
    __syncthreads();
  }

  // projection of x at time t (wave 0 only; xh must hold x_t)
  auto project = [&](int t) {
    if (j < 64) {
      const uint4* xv4 = (const uint4*)xh;
      float p0 = 0.f, p1 = 0.f, p2 = 0.f, p3 = 0.f;
#pragma unroll
      for (int c = 0; c < 4; ++c) {
        uint4 v = xv4[ps * 4 + c];
        p0 = dot2(wseg[4 * c + 0], v.x, p0);
        p1 = dot2(wseg[4 * c + 1], v.y, p1);
        p2 = dot2(wseg[4 * c + 2], v.z, p2);
        p3 = dot2(wseg[4 * c + 3], v.w, p3);
      }
      float p = (p0 + p1) + (p2 + p3);
      p += __shfl_down(p, 4, 8);
      p += __shfl_down(p, 2, 8);
      p += __shfl_down(p, 1, 8);
      if (ps == 0) out[((size_t)b * TSTEPS + t) * 8 + po] = p + bo;
    }
  };

  project(0);

  for (int k = 0; k < TSTEPS - 1; ++k) {
    // bu from uh (holds u[:,k])
    uint4 ua = *((const uint4*)uh), ub = *((const uint4*)(uh + 4));
    float s0 = dot2(Bh0.x, ua.x, 0.f); s0 = dot2(Bh0.y, ua.y, s0);
    s0 = dot2(Bh0.z, ua.z, s0);        s0 = dot2(Bh0.w, ua.w, s0);
    float s1 = dot2(Bh1.x, ub.x, 0.f); s1 = dot2(Bh1.y, ub.y, s1);
    s1 = dot2(Bh1.z, ub.z, s1);        s1 = dot2(Bh1.w, ub.w, s1);
    float bu = s0 + s1;

    float a0 = 0.f, a1 = 0.f, a2 = 0.f, a3 = 0.f;
    const uint4* xv4 = (const uint4*)xh;
#pragma unroll
    for (int c = 0; c < 32; ++c) {
      uint4 v = xv4[c];
      a0 = dot2(Ah[c].x, v.x, a0);
      a1 = dot2(Ah[c].y, v.y, a1);
      a2 = dot2(Ah[c].z, v.z, a2);
      a3 = dot2(Ah[c].w, v.w, a3);
    }
    float unext = 0.f;
    if (j < 16 && k + 1 < TSTEPS - 1)
      unext = u[((size_t)b * TSTEPS + (k + 1)) * NIN1 + j];

    float xn = x + tanh_f(bu + Cc + ((a0 + a1) + (a2 + a3))) - x * inv_et;
    __syncthreads();
    xh16[j] = (f16)xn;
    if (j < 16) uh16[j] = (f16)unext;
    x = xn;
    __syncthreads();

    project(k + 1);
  }
}

// ---------------------------------------------------------------------------
extern "C" void kernel_launch(void* const* d_in, const int* in_sizes, int n_in,
                              void* d_out, int out_size, void* d_ws, size_t ws_size,
                              hipStream_t stream)
{
  const float* u    = (const float*)d_in[0];
  const float* gWih = (const float*)d_in[1];
  const float* gWhh = (const float*)d_in[2];
  const float* gbih = (const float*)d_in[3];
  const float* gbhh = (const float*)d_in[4];
  const float* Wage = (const float*)d_in[5];
  const float* bage = (const float*)d_in[6];
  const float* Wih  = (const float*)d_in[7];
  const float* Whh  = (const float*)d_in[8];
  const float* bih  = (const float*)d_in[9];
  const float* bhh  = (const float*)d_in[10];
  const float* tau  = (const float*)d_in[11];
  const float* Wout = (const float*)d_in[12];
  const float* bout = (const float*)d_in[13];
  float* out = (float*)d_out;

  // ws layout: [dp chunk: bpc * DPAR f16][...][A2: 256*512 bf16 at the tail]
  const size_t A2_BYTES = (size_t)BATCH * 512 * 2;              // 256 KiB
  size_t a2_off = (ws_size > A2_BYTES + 4096)
                    ? ((ws_size - A2_BYTES) & ~(size_t)255) : 0;
  short* A2 = (short*)((char*)d_ws + a2_off);
  f16* dp = (f16*)d_ws;

  int bpc = (int)(a2_off / ((size_t)DPAR * sizeof(f16)));       // batch rows per chunk
  if (bpc < 1)     bpc = 1;        // degenerate tiny-ws fallback
  if (bpc > BATCH) bpc = BATCH;

  gru_kernel<<<BATCH, 512, 0, stream>>>(u, gWih, gWhh, gbih, gbhh, A2);

  for (int mb = 0; mb < BATCH; mb += bpc) {
    int nb = BATCH - mb; if (nb > bpc) nb = bpc;
    dim3 gg(DPAR / 128, (nb + 127) / 128);
    gemm_kernel<<<gg, 256, 0, stream>>>(A2, Wage, bage, Wih, Whh, bih, bhh, dp, mb, nb);
    dyn_kernel<<<nb, 256, 0, stream>>>(dp, mb, u, tau, Wout, bout, out);
  }
}

// Round 6
// 1550.725 us; speedup vs baseline: 3.7101x; 1.8914x over previous
//
#include <hip/hip_runtime.h>
#include <hip/hip_bf16.h>

#define BATCH  256
#define TSTEPS 501
#define NIN1   17
#define NH     256
#define DPAR   69888
#define KAUG   288   // 256 h + 17 x + 15 pad
#define HKAUG  144
#define FPIT   100

typedef _Float16 f16;
typedef f16   f16x2  __attribute__((ext_vector_type(2)));
typedef f16   f16x8  __attribute__((ext_vector_type(8)));
typedef short bf16x8 __attribute__((ext_vector_type(8)));
typedef float f32x4  __attribute__((ext_vector_type(4)));

__device__ __forceinline__ float dot2(unsigned w, unsigned v, float c) {
#if __has_builtin(__builtin_amdgcn_fdot2)
  return __builtin_amdgcn_fdot2(__builtin_bit_cast(f16x2, w), __builtin_bit_cast(f16x2, v), c, false);
#else
  f16x2 a = __builtin_bit_cast(f16x2, w), b = __builtin_bit_cast(f16x2, v);
  return c + (float)a[0] * (float)b[0] + (float)a[1] * (float)b[1];
#endif
}

__device__ __forceinline__ unsigned packh2(float a, float b) {
  f16x2 v; v[0] = (f16)a; v[1] = (f16)b;
  return __builtin_bit_cast(unsigned, v);
}

__device__ __forceinline__ short f2bf(float x) {
  __hip_bfloat16 b = __float2bfloat16(x);
  return __builtin_bit_cast(short, b);
}
__device__ __forceinline__ float bfs2f(short s) {
  return __bfloat162float(__builtin_bit_cast(__hip_bfloat16, s));
}

__device__ __forceinline__ float sigm(float x) { return 1.f / (1.f + __expf(-x)); }
__device__ __forceinline__ float tanh_f(float x) {
  float e = __expf(2.f * x);
  return 1.f - 2.f / (e + 1.f);
}

// ---------------------------------------------------------------------------
// Kernel 1: GRU recurrence. One block per batch element, 512 threads.
// u[b] preloaded to LDS as f16 (no global ops inside the step loop -> barriers
// never drain vmcnt). Thread (j,hf) owns the hf-half of gate rows
// {j, j+256, j+512}. [h|x] broadcast vector in LDS (f16).
// ---------------------------------------------------------------------------
__global__ __launch_bounds__(512, 2) void gru_kernel(
    const float* __restrict__ u,
    const float* __restrict__ gWih,
    const float* __restrict__ gWhh,
    const float* __restrict__ gbih,
    const float* __restrict__ gbhh,
    short* __restrict__ A2)   // bf16 hi/lo pair output, bit-cast as short
{
  const int b   = blockIdx.x;
  const int tid = threadIdx.x;
  const int j   = tid & 255;
  const int hf  = tid >> 8;

  __shared__ __align__(16) unsigned vecu[KAUG / 2];  // [h(256) | x(17) | pad] f16
  __shared__ float part_r[NH], part_z[NH], part_nh[NH], part_ni[NH];
  __shared__ __align__(16) f16 ubuf[TSTEPS * NIN1 + 15];  // u[b] as f16

  // preload u for this batch element (contiguous flat copy)
  {
    const float* ub = u + (size_t)b * TSTEPS * NIN1;
    for (int idx = tid; idx < TSTEPS * NIN1; idx += 512)
      ubuf[idx] = (f16)ub[idx];
  }

  unsigned wr[72], wz[72], wnh[72], wni[9];

  auto augw = [&](int g, int k) -> float {
    if (k < NH) return gWhh[g * NH + k];
    if (k < NH + NIN1) return gWih[g * NIN1 + (k - NH)];
    return 0.f;
  };

#pragma unroll
  for (int p = 0; p < 72; ++p) {
    int k = hf * HKAUG + 2 * p;
    wr[p] = packh2(augw(j, k), augw(j, k + 1));
    wz[p] = packh2(augw(j + 256, k), augw(j + 256, k + 1));
    float n0 = (k     < NH) ? gWhh[(j + 512) * NH + k]     : 0.f;
    float n1 = (k + 1 < NH) ? gWhh[(j + 512) * NH + k + 1] : 0.f;
    wnh[p] = packh2(n0, n1);  // hn dot: only k<256 (hidden part)
  }
#pragma unroll
  for (int p = 0; p < 9; ++p) {
    float a = 0.f, c = 0.f;
    if (hf == 1) {
      a = gWih[(j + 512) * NIN1 + 2 * p];
      if (2 * p + 1 < NIN1) c = gWih[(j + 512) * NIN1 + 2 * p + 1];
    }
    wni[p] = packh2(a, c);    // inn dot (input part), owned by hf==1
  }
  const float bias_r  = gbih[j]       + gbhh[j];
  const float bias_z  = gbih[j + 256] + gbhh[j + 256];
  const float bias_in = gbih[j + 512];
  const float bias_hn = gbhh[j + 512];

  float h = 0.f;
  {
    f16* vech = (f16*)vecu;
    if (hf == 0) vech[j] = (f16)0.f;            // h0 = 0
    else if (j < 32) vech[NH + j] = (f16)0.f;   // x slot zero/pad
  }
  __syncthreads();
  if (hf == 0 && j < NIN1) ((f16*)vecu)[NH + j] = ubuf[j];  // x_0
  __syncthreads();

  for (int t = 0; t < TSTEPS; ++t) {
    f16 xnext = (f16)0.f;
    if (hf == 0 && j < NIN1 && t + 1 < TSTEPS)
      xnext = ubuf[(t + 1) * NIN1 + j];         // LDS, not global

    float accR = 0.f, accZ = 0.f, accNH = 0.f, accNI = 0.f;
    const uint4* v4 = (const uint4*)(vecu + hf * (HKAUG / 2));
#pragma unroll
    for (int c = 0; c < 18; ++c) {
      uint4 v = v4[c];
      accR  = dot2(wr[4 * c + 0], v.x, accR);
      accR  = dot2(wr[4 * c + 1], v.y, accR);
      accR  = dot2(wr[4 * c + 2], v.z, accR);
      accR  = dot2(wr[4 * c + 3], v.w, accR);
      accZ  = dot2(wz[4 * c + 0], v.x, accZ);
      accZ  = dot2(wz[4 * c + 1], v.y, accZ);
      accZ  = dot2(wz[4 * c + 2], v.z, accZ);
      accZ  = dot2(wz[4 * c + 3], v.w, accZ);
      accNH = dot2(wnh[4 * c + 0], v.x, accNH);
      accNH = dot2(wnh[4 * c + 1], v.y, accNH);
      accNH = dot2(wnh[4 * c + 2], v.z, accNH);
      accNH = dot2(wnh[4 * c + 3], v.w, accNH);
    }
    if (hf == 1) {
      const uint4* vi = (const uint4*)(vecu + 128);  // x-part of vec
      uint4 va = vi[0], vb = vi[1];
      accNI = dot2(wni[0], va.x, accNI);
      accNI = dot2(wni[1], va.y, accNI);
      accNI = dot2(wni[2], va.z, accNI);
      accNI = dot2(wni[3], va.w, accNI);
      accNI = dot2(wni[4], vb.x, accNI);
      accNI = dot2(wni[5], vb.y, accNI);
      accNI = dot2(wni[6], vb.z, accNI);
      accNI = dot2(wni[7], vb.w, accNI);
      accNI = dot2(wni[8], vecu[136], accNI);
      part_r[j] = accR; part_z[j] = accZ; part_nh[j] = accNH; part_ni[j] = accNI;
    }
    __syncthreads();
    if (hf == 0) {
      float rp  = accR  + part_r[j]  + bias_r;
      float zp  = accZ  + part_z[j]  + bias_z;
      float hn  = accNH + part_nh[j] + bias_hn;
      float inn = part_ni[j] + bias_in;
      float r = sigm(rp), z = sigm(zp);
      float n = tanh_f(inn + r * hn);
      h = (1.f - z) * n + z * h;
      f16* vech = (f16*)vecu;
      vech[j] = (f16)h;
      if (j < NIN1) vech[NH + j] = xnext;
    }
    __syncthreads();
  }

  if (hf == 0) {  // hT as bf16 hi/lo pair -> A-operand of the dparams GEMM
    short hi = f2bf(h);
    A2[(size_t)b * 512 + j]       = hi;
    A2[(size_t)b * 512 + 256 + j] = f2bf(h - bfs2f(hi));
  }
}

// ---------------------------------------------------------------------------
// Kernel 2 (chunked over batch): for b in [mb, mb+nb):
// dp[b-mb] = [h_hi|h_lo] @ [Wage;Wage] + bage + {Wih|Whh|bih+bhh}, stored f16.
// Wage is fp32 -> converted to bf16 while staging to LDS. 128x128 tiles,
// 4 waves x (4x4) 16x16x32 bf16 MFMA. dp row: [Bm(4096) | A(65536) | C(256)].
// ---------------------------------------------------------------------------
__global__ __launch_bounds__(256, 2) void gemm_kernel(
    const short* __restrict__ A2,
    const float* __restrict__ Wage,
    const float* __restrict__ bage,
    const float* __restrict__ Wih,
    const float* __restrict__ Whh,
    const float* __restrict__ bih,
    const float* __restrict__ bhh,
    f16* __restrict__ dp, int mb, int nb)
{
  __shared__ __align__(16) short As[128 * 40];
  __shared__ __align__(16) short Bs[128 * 40];
  const int tid = threadIdx.x;
  const int n0 = blockIdx.x * 128, m0 = blockIdx.y * 128;
  const int w = tid >> 6, l = tid & 63;
  const int wm = w & 1, wn = w >> 1;
  const int lm = l & 15, lq = l >> 4;

  f32x4 acc[4][4] = {};

  for (int k0 = 0; k0 < 512; k0 += 32) {
    const int ksrc = k0 & 255;
#pragma unroll
    for (int r = 0; r < 2; ++r) {
      int idx = r * 256 + tid;
      int row = idx >> 2, q = idx & 3;
      int rowg = mb + m0 + row; if (rowg > 255) rowg = 255;   // clamp staging
      *((uint4*)(As + row * 40 + q * 8)) =
          *((const uint4*)(A2 + (size_t)rowg * 512 + k0 + q * 8));
      const float* wsrc = Wage + (size_t)(n0 + row) * 256 + ksrc + q * 8;
      f32x4 w0 = *((const f32x4*)wsrc);
      f32x4 w1 = *((const f32x4*)(wsrc + 4));
      bf16x8 pk;
      pk[0] = f2bf(w0[0]); pk[1] = f2bf(w0[1]); pk[2] = f2bf(w0[2]); pk[3] = f2bf(w0[3]);
      pk[4] = f2bf(w1[0]); pk[5] = f2bf(w1[1]); pk[6] = f2bf(w1[2]); pk[7] = f2bf(w1[3]);
      *((bf16x8*)(Bs + row * 40 + q * 8)) = pk;
    }
    __syncthreads();
    bf16x8 af[4], bfr[4];
#pragma unroll
    for (int i = 0; i < 4; ++i)
      af[i] = *((const bf16x8*)(As + (wm * 64 + i * 16 + lm) * 40 + lq * 8));
#pragma unroll
    for (int i = 0; i < 4; ++i)
      bfr[i] = *((const bf16x8*)(Bs + (wn * 64 + i * 16 + lm) * 40 + lq * 8));
#pragma unroll
    for (int i = 0; i < 4; ++i)
#pragma unroll
      for (int jn = 0; jn < 4; ++jn)
        acc[i][jn] = __builtin_amdgcn_mfma_f32_16x16x32_bf16(af[i], bfr[jn], acc[i][jn], 0, 0, 0);
    __syncthreads();
  }

  // fused repack: per-column additive term (4 columns per lane)
  float addv[4];
#pragma unroll
  for (int jn = 0; jn < 4; ++jn) {
    int d = n0 + wn * 64 + jn * 16 + lm;
    float a = bage[d];
    if (d < 4096)       a += Wih[d];
    else if (d < 69632) a += Whh[d - 4096];
    else                a += bih[d - 69632] + bhh[d - 69632];
    addv[jn] = a;
  }

#pragma unroll
  for (int i = 0; i < 4; ++i)
#pragma unroll
    for (int jn = 0; jn < 4; ++jn)
#pragma unroll
      for (int rr = 0; rr < 4; ++rr) {
        int mloc = m0 + wm * 64 + i * 16 + lq * 4 + rr;  // C/D: row=(lane>>4)*4+reg
        int n = n0 + wn * 64 + jn * 16 + lm;             //      col=lane&15
        if (mloc < nb)
          dp[(size_t)mloc * DPAR + n] = (f16)(acc[i][jn][rr] + addv[jn]);
      }
}

// ---------------------------------------------------------------------------
// Kernel 3 (chunked): fixed point (100) + Euler (500) + fused Wout projection.
// One block per b, 256 threads. Thread j holds its A-row as 128 packed f16
// pairs (v_dot2_f32_f16). x double-buffered in LDS (1 barrier/iter); u[b]
// preloaded to LDS; outputs staged in LDS and flushed once -> NO global memory
// ops inside the loops, so barriers never drain vmcnt. Projection distributed
// across all 4 waves (wave w -> outputs 2w, 2w+1).
// ---------------------------------------------------------------------------
__global__ __launch_bounds__(256, 2) void dyn_kernel(
    const f16* __restrict__ dp, int mb,
    const float* __restrict__ u,
    const float* __restrict__ tau,
    const float* __restrict__ Wout,
    const float* __restrict__ bout,
    float* __restrict__ out)
{
  const int b = mb + blockIdx.x;
  const int j = threadIdx.x;
  const f16* __restrict__ base = dp + (size_t)blockIdx.x * DPAR;

  __shared__ __align__(16) unsigned xbuf[2][128];   // x as f16 pairs, dbuf
  __shared__ __align__(16) unsigned uf[TSTEPS * 8]; // u[b][:, :16] as f16 pairs
  __shared__ __align__(16) float ob[TSTEPS * 8];    // staged outputs

  // preload u (first 16 of 17 inputs are used by Bm)
  {
    f16* uf16 = (f16*)uf;
    const float* ub = u + (size_t)b * TSTEPS * NIN1;
    for (int idx = j; idx < TSTEPS * 16; idx += 256) {
      int t = idx >> 4, i = idx & 15;
      uf16[idx] = (f16)ub[t * NIN1 + i];
    }
  }

  uint4 Ah[32];                       // A-row: 256 f16 = 32 uint4 = 128 VGPRs
#pragma unroll
  for (int c = 0; c < 32; ++c)
    Ah[c] = *((const uint4*)(base + 4096 + j * 256 + c * 8));
  uint4 Bh0 = *((const uint4*)(base + j * 16));
  uint4 Bh1 = *((const uint4*)(base + j * 16 + 8));
  const float Cc = (float)base[69632 + j];
  const float et = __expf(tau[j]);
  const float inv_et = 1.f / et;

  // projection operands: wave w -> outputs {2w, 2w+1}; 32 lanes per output
  const int l = j & 63, wv = j >> 6;
  const int po = 2 * wv + (l >> 5), ps = l & 31;
  uint4 wseg;                          // Wout[po][ps*8 .. ps*8+7] packed
  {
    const float* wp = Wout + po * 256 + ps * 8;
    wseg.x = packh2(wp[0], wp[1]); wseg.y = packh2(wp[2], wp[3]);
    wseg.z = packh2(wp[4], wp[5]); wseg.w = packh2(wp[6], wp[7]);
  }
  const float bo = bout[po];

  if (j < 128) { xbuf[0][j] = 0u; xbuf[1][j] = 0u; }
  __syncthreads();

  auto bu_at = [&](int t) -> float {
    const uint4* up = (const uint4*)(uf + t * 8);
    uint4 ua = up[0], ub4 = up[1];
    float s0 = dot2(Bh0.x, ua.x, 0.f);  s0 = dot2(Bh0.y, ua.y, s0);
    s0 = dot2(Bh0.z, ua.z, s0);         s0 = dot2(Bh0.w, ua.w, s0);
    float s1 = dot2(Bh1.x, ub4.x, 0.f); s1 = dot2(Bh1.y, ub4.y, s1);
    s1 = dot2(Bh1.z, ub4.z, s1);        s1 = dot2(Bh1.w, ub4.w, s1);
    return s0 + s1;
  };
  const float bu0 = bu_at(0);

  int cur = 0;
  float x = 0.f;
  for (int it = 0; it < FPIT; ++it) {
    float a0 = 0.f, a1 = 0.f, a2 = 0.f, a3 = 0.f;
    const uint4* xp = (const uint4*)xbuf[cur];
#pragma unroll
    for (int c = 0; c < 32; ++c) {
      uint4 v = xp[c];
      a0 = dot2(Ah[c].x, v.x, a0);
      a1 = dot2(Ah[c].y, v.y, a1);
      a2 = dot2(Ah[c].z, v.z, a2);
      a3 = dot2(Ah[c].w, v.w, a3);
    }
    x = et * tanh_f(bu0 + Cc + ((a0 + a1) + (a2 + a3)));
    ((f16*)xbuf[cur ^ 1])[j] = (f16)x;
    __syncthreads();
    cur ^= 1;
  }
  // xbuf[cur] now holds x0

  auto project = [&](int t) {
    const uint4* xp = (const uint4*)xbuf[cur];
    uint4 v = xp[ps];
    float p = dot2(wseg.x, v.x, 0.f);
    p = dot2(wseg.y, v.y, p);
    p = dot2(wseg.z, v.z, p);
    p = dot2(wseg.w, v.w, p);
    p += __shfl_down(p, 16, 32);
    p += __shfl_down(p, 8, 32);
    p += __shfl_down(p, 4, 32);
    p += __shfl_down(p, 2, 32);
    p += __shfl_down(p, 1, 32);
    if (ps == 0) ob[t * 8 + po] = p + bo;
  };

  for (int k = 0; k < TSTEPS - 1; ++k) {
    float bu = bu_at(k);
    float a0 = 0.f, a1 = 0.f, a2 = 0.f, a3 = 0.f;
    const uint4* xp = (const uint4*)xbuf[cur];
#pragma unroll
    for (int c = 0; c < 32; ++c) {
      uint4 v = xp[c];
      a0 = dot2(Ah[c].x, v.x, a0);
      a1 = dot2(Ah[c].y, v.y, a1);
      a2 = dot2(Ah[c].z, v.z, a2);
      a3 = dot2(Ah[c].w, v.w, a3);
    }
    float xn = x + tanh_f(bu + Cc + ((a0 + a1) + (a2 + a3))) - x * inv_et;
    ((f16*)xbuf[cur ^ 1])[j] = (f16)xn;
    project(k);                 // projects x_k from xbuf[cur]
    x = xn;
    __syncthreads();
    cur ^= 1;
  }
  project(TSTEPS - 1);
  __syncthreads();

  // flush staged outputs (coalesced)
  {
    float* og = out + (size_t)b * TSTEPS * 8;
    for (int idx = j; idx < TSTEPS * 8; idx += 256) og[idx] = ob[idx];
  }
}

// ---------------------------------------------------------------------------
extern "C" void kernel_launch(void* const* d_in, const int* in_sizes, int n_in,
                              void* d_out, int out_size, void* d_ws, size_t ws_size,
                              hipStream_t stream)
{
  const float* u    = (const float*)d_in[0];
  const float* gWih = (const float*)d_in[1];
  const float* gWhh = (const float*)d_in[2];
  const float* gbih = (const float*)d_in[3];
  const float* gbhh = (const float*)d_in[4];
  const float* Wage = (const float*)d_in[5];
  const float* bage = (const float*)d_in[6];
  const float* Wih  = (const float*)d_in[7];
  const float* Whh  = (const float*)d_in[8];
  const float* bih  = (const float*)d_in[9];
  const float* bhh  = (const float*)d_in[10];
  const float* tau  = (const float*)d_in[11];
  const float* Wout = (const float*)d_in[12];
  const float* bout = (const float*)d_in[13];
  float* out = (float*)d_out;

  // ws layout: [dp chunk: bpc * DPAR f16][...][A2: 256*512 bf16 at the tail]
  const size_t A2_BYTES = (size_t)BATCH * 512 * 2;              // 256 KiB
  size_t a2_off = (ws_size > A2_BYTES + 4096)
                    ? ((ws_size - A2_BYTES) & ~(size_t)255) : 0;
  short* A2 = (short*)((char*)d_ws + a2_off);
  f16* dp = (f16*)d_ws;

  int bpc = (int)(a2_off / ((size_t)DPAR * sizeof(f16)));       // batch rows per chunk
  if (bpc < 1)     bpc = 1;        // degenerate tiny-ws fallback
  if (bpc > BATCH) bpc = BATCH;

  gru_kernel<<<BATCH, 512, 0, stream>>>(u, gWih, gWhh, gbih, gbhh, A2);

  for (int mb = 0; mb < BATCH; mb += bpc) {
    int nb = BATCH - mb; if (nb > bpc) nb = bpc;
    dim3 gg(DPAR / 128, (nb + 127) / 128);
    gemm_kernel<<<gg, 256, 0, stream>>>(A2, Wage, bage, Wih, Whh, bih, bhh, dp, mb, nb);
    dyn_kernel<<<nb, 256, 0, stream>>>(dp, mb, u, tau, Wout, bout, out);
  }
}